// Round 4
// baseline (955.655 us; speedup 1.0000x reference)
//
#include <hip/hip_runtime.h>
#include <stdint.h>

#define M_DIM 2048
#define K_DIM 8192
#define N_Q   8192
#define N_KV  1024
#define N_TOT (N_Q + 2 * N_KV)   // 10240
#define BM    128
#define BN    128
#define BK    32
#define NIT   (K_DIM / BK)       // 256 K-iterations

typedef __bf16 bf16x8 __attribute__((ext_vector_type(8)));
typedef __bf16 bf16x2 __attribute__((ext_vector_type(2)));
typedef float  f32x4  __attribute__((ext_vector_type(4)));

// ---------------------------------------------------------------------------
// Pass 1a: cast x f32 -> bf16 (row-major [M][K] unchanged)
// ---------------------------------------------------------------------------
__global__ __launch_bounds__(256) void xcast(const float* __restrict__ x,
                                             __bf16* __restrict__ xb) {
    size_t i = ((size_t)blockIdx.x * 256 + threadIdx.x) * 8;
    f32x4 a = *(const f32x4*)(x + i);
    f32x4 b = *(const f32x4*)(x + i + 4);
    bf16x8 o = { (__bf16)a.x, (__bf16)a.y, (__bf16)a.z, (__bf16)a.w,
                 (__bf16)b.x, (__bf16)b.y, (__bf16)b.z, (__bf16)b.w };
    *(bf16x8*)(xb + i) = o;
}

// ---------------------------------------------------------------------------
// Pass 1b: cast + transpose W (f32 [K][N] -> bf16 [N][K]), q|k|v concatenated
// along N (cdst = concatenated index; csrc local to source matrix).
// 64x64 tiles via LDS; stride 65 dwords -> conflict-light on both sides.
// (verified round 2/3 — unchanged)
// ---------------------------------------------------------------------------
__global__ __launch_bounds__(256) void wcast_t(const float* __restrict__ wq,
                                               const float* __restrict__ wk,
                                               const float* __restrict__ wv,
                                               __bf16* __restrict__ wt) {
    __shared__ float sT[64 * 65];
    const uint32_t bid   = blockIdx.x;
    const uint32_t ktile = bid & 127;   // 8192/64 = 128 k-tiles (fast-moving)
    const uint32_t ntile = bid >> 7;    // 160 n-tiles
    const float* W; uint32_t ldW, csrc, cdst;
    if (ntile < 128)      { W = wq; ldW = N_Q;  csrc = ntile * 64;
                            cdst = csrc; }
    else if (ntile < 144) { W = wk; ldW = N_KV; csrc = (ntile - 128) * 64;
                            cdst = N_Q + csrc; }
    else                  { W = wv; ldW = N_KV; csrc = (ntile - 144) * 64;
                            cdst = N_Q + N_KV + csrc; }
    const uint32_t k0 = ktile * 64;
    const uint32_t t  = threadIdx.x;

    // load 64 rows x 64 cols f32, coalesced (16 lanes x 16B = 256B per row)
    const uint32_t lr = t >> 4;
    const uint32_t lc = (t & 15) * 4;
    const float* gp = W + (size_t)(k0 + lr) * ldW + csrc + lc;
    #pragma unroll
    for (int i = 0; i < 4; ++i) {
        f32x4 v = *(const f32x4*)(gp + (size_t)i * 16 * ldW);
        float* d = &sT[(lr + i * 16) * 65 + lc];
        d[0] = v.x; d[1] = v.y; d[2] = v.z; d[3] = v.w;
    }
    __syncthreads();

    // write 64 n-rows of WT, 64 k each; 8 lanes x bf16x8 = 128B per n-row
    const uint32_t wn  = t >> 3;       // 0..31 (+32 on 2nd pass)
    const uint32_t wk8 = (t & 7) * 8;  // k offset
    #pragma unroll
    for (int it = 0; it < 2; ++it) {
        uint32_t n = wn + it * 32;
        bf16x8 o;
        #pragma unroll
        for (int j = 0; j < 8; ++j) o[j] = (__bf16)sT[(wk8 + j) * 65 + n];
        *(bf16x8*)(wt + (size_t)(cdst + n) * K_DIM + k0 + wk8) = o;
    }
}

// ---------------------------------------------------------------------------
// Pass 2: bf16 B^T GEMM, 128x128 tile, BK=32, 4 waves 2x2, global_load_lds.
// NEW vs round 3 (T4): 3-buffer LDS pipeline with COUNTED vmcnt + raw
// s_barrier — loads stay in flight across barriers (never vmcnt(0) in the
// steady-state loop). Per iter: wait vmcnt(4) (own tile-kt loads done; other
// waves guarantee theirs via their own wait + the barrier), s_barrier, then
// stage tile kt+2 into buf[(kt+2)%3] (last read before the PREVIOUS barrier
// -> no race), then ds_read frags + 16 MFMA from buf[kt%3].
// Swizzle (rule #21, verified): LDS dest linear, global SOURCE chunk
// pre-XOR'd by swz(r)=(r>>1)&3, frag ds_read applies the same XOR.
// ---------------------------------------------------------------------------
__device__ __forceinline__ void gload16(const void* g, void* l) {
    __builtin_amdgcn_global_load_lds(
        (const __attribute__((address_space(1))) void*)g,
        (__attribute__((address_space(3))) void*)l, 16, 0, 0);
}

#define TILE_ELTS (BM * BK)          // 4096 bf16 = 8192 B per buffer

__global__ __launch_bounds__(256) void qkv_mm(const __bf16* __restrict__ xb,
                                              const __bf16* __restrict__ wt,
                                              float* __restrict__ out) {
    __shared__ __align__(16) __bf16 sA[3][TILE_ELTS];   // [m][k], chunk-swizzled
    __shared__ __align__(16) __bf16 sB[3][TILE_ELTS];   // [n][k], chunk-swizzled

    const uint32_t tid = threadIdx.x;

    // XCD-bijective swizzle (1280 % 8 == 0): each XCD owns 10 consecutive
    // n-tiles (all 16 m-tiles) -> W slab reuse stays inside one L2.
    const uint32_t logical = (blockIdx.x & 7) * 160 + (blockIdx.x >> 3);
    const uint32_t mt = logical & 15;   // 16 m-tiles contiguous per n-tile
    const uint32_t nt = logical >> 4;   // 80 n-tiles
    const uint32_t m0 = mt * BM;
    const uint32_t n0 = nt * BN;

    // ---- staging maps: chunk c = w*128 + i*64 + lane; row = c>>2; LDS chunk
    // position (c&3) receives global chunk (c&3)^swz(row). LDS dest linear.
    const uint32_t w    = tid >> 6;
    const uint32_t lane = tid & 63;
    const __bf16* gA[2];
    const __bf16* gB[2];
    #pragma unroll
    for (int i = 0; i < 2; ++i) {
        uint32_t c  = w * 128 + i * 64 + lane;
        uint32_t r  = c >> 2;
        uint32_t qs = (c & 3) ^ ((r >> 1) & 3);
        gA[i] = xb + (size_t)(m0 + r) * K_DIM + qs * 8;
        gB[i] = wt + (size_t)(n0 + r) * K_DIM + qs * 8;
    }
    // wave-uniform LDS staging bases, per buffer
    char* laA[3]; char* laB[3];
    #pragma unroll
    for (int b = 0; b < 3; ++b) {
        laA[b] = (char*)(&sA[b][0]) + w * 2048;
        laB[b] = (char*)(&sB[b][0]) + w * 2048;
    }

    // ---- wave / lane decomposition (2x2 waves, each 64x64) ----
    const uint32_t wm   = (w >> 1) * 64;
    const uint32_t wn   = (w & 1) * 64;
    const uint32_t l15  = lane & 15;
    const uint32_t quad = lane >> 4;

    // frag read offsets (bf16 units, within one buffer): row*32 + (quad^swz)*8
    uint32_t a_off[4], b_off[4];
    #pragma unroll
    for (int t = 0; t < 4; ++t) {
        uint32_t ar = wm + t * 16 + l15;
        a_off[t] = ar * BK + ((quad ^ ((ar >> 1) & 3)) * 8);
        uint32_t br = wn + t * 16 + l15;
        b_off[t] = br * BK + ((quad ^ ((br >> 1) & 3)) * 8);
    }

    f32x4 acc[4][4] = {};

    auto STAGE = [&](uint32_t b) {
        gload16(gA[0], laA[b]); gload16(gA[1], laA[b] + 1024);
        gload16(gB[0], laB[b]); gload16(gB[1], laB[b] + 1024);
        gA[0] += BK; gA[1] += BK; gB[0] += BK; gB[1] += BK;
    };

    // ---- prologue: tiles 0,1 in flight (8 outstanding loads/thread) ----
    STAGE(0);
    STAGE(1);

    uint32_t rd = 0;   // buffer holding tile kt
    for (uint32_t kt = 0; kt < NIT; ++kt) {
        // own tile-kt loads done; others' guaranteed by their wait + barrier
        if (kt + 1 < NIT) {
            asm volatile("s_waitcnt vmcnt(4)" ::: "memory");
        } else {
            asm volatile("s_waitcnt vmcnt(0)" ::: "memory");
        }
        __builtin_amdgcn_sched_barrier(0);
        __builtin_amdgcn_s_barrier();
        __builtin_amdgcn_sched_barrier(0);

        // stage tile kt+2 into buf (rd+2)%3 == buf of tile kt-1 (all waves
        // finished reading it before the barrier above)
        if (kt + 2 < NIT) STAGE(rd >= 1 ? rd - 1 : 2);

        const __bf16* pA = &sA[rd][0];
        const __bf16* pB = &sB[rd][0];
        bf16x8 af[4], bfr[4];
        #pragma unroll
        for (int t = 0; t < 4; ++t) {
            af[t]  = *(const bf16x8*)(pA + a_off[t]);
            bfr[t] = *(const bf16x8*)(pB + b_off[t]);
        }
        #pragma unroll
        for (int mi = 0; mi < 4; ++mi)
            #pragma unroll
            for (int ni = 0; ni < 4; ++ni)
                acc[mi][ni] = __builtin_amdgcn_mfma_f32_16x16x32_bf16(
                    af[mi], bfr[ni], acc[mi][ni], 0, 0, 0);

        rd = (rd == 2) ? 0 : rd + 1;
    }

    // ---- epilogue: head nt slab is contiguous [2048][128] f32 ----
    // C/D layout: col = lane&15, row = quad*4 + reg (m89/m91 verified)
    float* op = out + (size_t)nt * (M_DIM * 128) + (size_t)m0 * 128;
    #pragma unroll
    for (int mi = 0; mi < 4; ++mi) {
        #pragma unroll
        for (int r = 0; r < 4; ++r) {
            uint32_t row = wm + mi * 16 + quad * 4 + r;
            #pragma unroll
            for (int ni = 0; ni < 4; ++ni) {
                uint32_t col = wn + ni * 16 + l15;
                op[(size_t)row * 128 + col] = acc[mi][ni][r];
            }
        }
    }
}

// ---------------------------------------------------------------------------
// Fallback (round-0 verified kernel): used only if ws_size is too small.
// ---------------------------------------------------------------------------
__device__ __forceinline__ uint32_t swz_fb(uint32_t r) { return ((r >> 1) ^ (r >> 3)) & 3u; }

__device__ __forceinline__ uint32_t pack_bf16(float lo, float hi) {
    bf16x2 v = { (__bf16)lo, (__bf16)hi };
    return __builtin_bit_cast(uint32_t, v);
}

__global__ __launch_bounds__(256) void qkv_gemm(
    const float* __restrict__ x,
    const float* __restrict__ wq,
    const float* __restrict__ wk,
    const float* __restrict__ wv,
    float* __restrict__ out)
{
    __shared__ __align__(16) uint16_t sA[BM * BK];
    __shared__ __align__(16) uint16_t sB[BN * BK];
    uint32_t* sAu = (uint32_t*)sA;
    uint32_t* sBu = (uint32_t*)sB;

    const uint32_t tid    = threadIdx.x;
    const uint32_t bid    = blockIdx.x;
    const uint32_t mt_blk = bid & 15;
    const uint32_t nt_blk = bid >> 4;
    const uint32_t m0     = mt_blk * BM;

    const size_t QSZ = (size_t)64 * M_DIM * 128;
    const size_t KSZ = (size_t)8  * M_DIM * 128;
    const float* Wsel;
    uint32_t ldW, col0;
    size_t obase;
    if (nt_blk < 64)      { Wsel = wq; ldW = N_Q;  col0 = nt_blk * 128;
                            obase = (size_t)nt_blk * M_DIM * 128; }
    else if (nt_blk < 72) { Wsel = wk; ldW = N_KV; col0 = (nt_blk - 64) * 128;
                            obase = QSZ + (size_t)(nt_blk - 64) * M_DIM * 128; }
    else                  { Wsel = wv; ldW = N_KV; col0 = (nt_blk - 72) * 128;
                            obase = QSZ + KSZ + (size_t)(nt_blk - 72) * M_DIM * 128; }

    const float* agp = x + (size_t)(m0 + (tid >> 3)) * K_DIM + (tid & 7) * 4;
    uint32_t a_wr[4];
    #pragma unroll
    for (int i = 0; i < 4; ++i) {
        uint32_t r = i * 32 + (tid >> 3);
        a_wr[i] = r * 16 + ((((tid >> 1) & 3) ^ swz_fb(r)) * 4) + (tid & 1) * 2;
    }

    const uint32_t bk  = (tid >> 4) * 2;
    const uint32_t bn0 = (tid & 15) * 8;
    const float* bgp = Wsel + (size_t)bk * ldW + col0 + bn0;
    const uint32_t bkc = bk >> 3;
    const uint32_t bkd = (bk & 7) >> 1;

    f32x4 apre[4], bpre[4];
    #pragma unroll
    for (int i = 0; i < 4; ++i) apre[i] = *(const f32x4*)(agp + (size_t)i * 32 * K_DIM);
    bpre[0] = *(const f32x4*)(bgp);
    bpre[1] = *(const f32x4*)(bgp + 4);
    bpre[2] = *(const f32x4*)(bgp + ldW);
    bpre[3] = *(const f32x4*)(bgp + ldW + 4);

    const uint32_t lane = tid & 63;
    const uint32_t wid  = tid >> 6;
    const uint32_t wm   = (wid >> 1) * 64;
    const uint32_t wn   = (wid & 1) * 64;
    const uint32_t l15  = lane & 15;
    const uint32_t quad = lane >> 4;

    f32x4 acc[4][4] = {};

    uint32_t a_off[4], b_off[4];
    #pragma unroll
    for (int t = 0; t < 4; ++t) {
        uint32_t ar = wm + t * 16 + l15;
        a_off[t] = ar * BK + ((quad ^ swz_fb(ar)) * 8);
        uint32_t br = wn + t * 16 + l15;
        b_off[t] = br * BK + ((quad ^ swz_fb(br)) * 8);
    }

    const float* agp_n = agp + BK;
    const float* bgp_n = bgp + (size_t)BK * ldW;

    for (uint32_t kt = 0; kt < NIT; ++kt) {
        __syncthreads();

        #pragma unroll
        for (int i = 0; i < 4; ++i) {
            uint2 wv2;
            wv2.x = pack_bf16(apre[i].x, apre[i].y);
            wv2.y = pack_bf16(apre[i].z, apre[i].w);
            *(uint2*)&sAu[a_wr[i]] = wv2;
        }
        {
            const float* pk0 = (const float*)&bpre[0];
            const float* pk1 = (const float*)&bpre[2];
            #pragma unroll
            for (int j = 0; j < 8; ++j) {
                uint32_t n = bn0 + j;
                sBu[n * 16 + ((bkc ^ swz_fb(n)) * 4) + bkd] = pack_bf16(pk0[j], pk1[j]);
            }
        }

        if (kt + 1 < NIT) {
            #pragma unroll
            for (int i = 0; i < 4; ++i) apre[i] = *(const f32x4*)(agp_n + (size_t)i * 32 * K_DIM);
            bpre[0] = *(const f32x4*)(bgp_n);
            bpre[1] = *(const f32x4*)(bgp_n + 4);
            bpre[2] = *(const f32x4*)(bgp_n + ldW);
            bpre[3] = *(const f32x4*)(bgp_n + ldW + 4);
            agp_n += BK;
            bgp_n += (size_t)BK * ldW;
        }

        __syncthreads();

        bf16x8 af[4], bf[4];
        #pragma unroll
        for (int t = 0; t < 4; ++t) {
            af[t] = *(const bf16x8*)(sA + a_off[t]);
            bf[t] = *(const bf16x8*)(sB + b_off[t]);
        }
        #pragma unroll
        for (int mi = 0; mi < 4; ++mi)
            #pragma unroll
            for (int ni = 0; ni < 4; ++ni)
                acc[mi][ni] = __builtin_amdgcn_mfma_f32_16x16x32_bf16(
                    af[mi], bf[ni], acc[mi][ni], 0, 0, 0);
    }

    float* op = out + obase + (size_t)m0 * 128;
    #pragma unroll
    for (int mi = 0; mi < 4; ++mi) {
        #pragma unroll
        for (int r = 0; r < 4; ++r) {
            uint32_t row = wm + mi * 16 + quad * 4 + r;
            #pragma unroll
            for (int ni = 0; ni < 4; ++ni) {
                uint32_t col = wn + ni * 16 + l15;
                op[(size_t)row * 128 + col] = acc[mi][ni][r];
            }
        }
    }
}

extern "C" void kernel_launch(void* const* d_in, const int* in_sizes, int n_in,
                              void* d_out, int out_size, void* d_ws, size_t ws_size,
                              hipStream_t stream) {
    const float* x  = (const float*)d_in[0];
    const float* wq = (const float*)d_in[1];
    const float* wk = (const float*)d_in[2];
    const float* wv = (const float*)d_in[3];

    const size_t XB_BYTES = (size_t)M_DIM * K_DIM * 2;          //  33.6 MB
    const size_t WT_BYTES = (size_t)N_TOT * K_DIM * 2;          // 167.8 MB

    if (ws_size >= XB_BYTES + WT_BYTES) {
        __bf16* xb = (__bf16*)d_ws;
        __bf16* wt = (__bf16*)((char*)d_ws + XB_BYTES);
        xcast<<<dim3((M_DIM * K_DIM) / (256 * 8)), dim3(256), 0, stream>>>(x, xb);
        wcast_t<<<dim3((K_DIM / 64) * (N_TOT / 64)), dim3(256), 0, stream>>>(wq, wk, wv, wt);
        qkv_mm<<<dim3((M_DIM / BM) * (N_TOT / BN)), dim3(256), 0, stream>>>(xb, wt, (float*)d_out);
    } else {
        qkv_gemm<<<dim3((M_DIM / BM) * (N_TOT / BN)), dim3(256), 0, stream>>>(
            x, wq, wk, wv, (float*)d_out);
    }
}

// Round 5
// 944.587 us; speedup vs baseline: 1.0117x; 1.0117x over previous
//
#include <hip/hip_runtime.h>
#include <stdint.h>

#define M_DIM 2048
#define K_DIM 8192
#define N_Q   8192
#define N_KV  1024
#define N_TOT (N_Q + 2 * N_KV)   // 10240

typedef __bf16 bf16x8 __attribute__((ext_vector_type(8)));
typedef __bf16 bf16x2 __attribute__((ext_vector_type(2)));
typedef float  f32x4  __attribute__((ext_vector_type(4)));

// ---------------------------------------------------------------------------
// Pass 1a: cast x f32 -> bf16 (verified r2/r3, unchanged)
// ---------------------------------------------------------------------------
__global__ __launch_bounds__(256) void xcast(const float* __restrict__ x,
                                             __bf16* __restrict__ xb) {
    size_t i = ((size_t)blockIdx.x * 256 + threadIdx.x) * 8;
    f32x4 a = *(const f32x4*)(x + i);
    f32x4 b = *(const f32x4*)(x + i + 4);
    bf16x8 o = { (__bf16)a.x, (__bf16)a.y, (__bf16)a.z, (__bf16)a.w,
                 (__bf16)b.x, (__bf16)b.y, (__bf16)b.z, (__bf16)b.w };
    *(bf16x8*)(xb + i) = o;
}

// ---------------------------------------------------------------------------
// Pass 1b: cast + transpose W -> bf16 [N][K] concat (verified r2/r3, unchanged)
// ---------------------------------------------------------------------------
__global__ __launch_bounds__(256) void wcast_t(const float* __restrict__ wq,
                                               const float* __restrict__ wk,
                                               const float* __restrict__ wv,
                                               __bf16* __restrict__ wt) {
    __shared__ float sT[64 * 65];
    const uint32_t bid   = blockIdx.x;
    const uint32_t ktile = bid & 127;
    const uint32_t ntile = bid >> 7;
    const float* W; uint32_t ldW, csrc, cdst;
    if (ntile < 128)      { W = wq; ldW = N_Q;  csrc = ntile * 64;
                            cdst = csrc; }
    else if (ntile < 144) { W = wk; ldW = N_KV; csrc = (ntile - 128) * 64;
                            cdst = N_Q + csrc; }
    else                  { W = wv; ldW = N_KV; csrc = (ntile - 144) * 64;
                            cdst = N_Q + N_KV + csrc; }
    const uint32_t k0 = ktile * 64;
    const uint32_t t  = threadIdx.x;

    const uint32_t lr = t >> 4;
    const uint32_t lc = (t & 15) * 4;
    const float* gp = W + (size_t)(k0 + lr) * ldW + csrc + lc;
    #pragma unroll
    for (int i = 0; i < 4; ++i) {
        f32x4 v = *(const f32x4*)(gp + (size_t)i * 16 * ldW);
        float* d = &sT[(lr + i * 16) * 65 + lc];
        d[0] = v.x; d[1] = v.y; d[2] = v.z; d[3] = v.w;
    }
    __syncthreads();

    const uint32_t wn  = t >> 3;
    const uint32_t wk8 = (t & 7) * 8;
    #pragma unroll
    for (int it = 0; it < 2; ++it) {
        uint32_t n = wn + it * 32;
        bf16x8 o;
        #pragma unroll
        for (int j = 0; j < 8; ++j) o[j] = (__bf16)sT[(wk8 + j) * 65 + n];
        *(bf16x8*)(wt + (size_t)(cdst + n) * K_DIM + k0 + wk8) = o;
    }
}

// ---------------------------------------------------------------------------
// Pass 2: 8-phase 256x256 bf16 GEMM (T2+T3+T4+T5).
// 8 waves (2M x 4N), per-wave 128x64 out. BK=64 as two 32-k halves.
// LDS 128 KiB: S = A[2buf][2kh][256][32] | B[2buf][2kh][256][32] (bf16).
// Per phase: 4-8 ds_read_b128 + stage 1 half-tile (2x global_load_lds 16B)
//            + bar + setprio(1) + 16 MFMA + setprio(0) + bar.
// Stage leads first-read by 5-6 phases; vmcnt(6) at odd phases provably
// drains each half >=1 barrier before its first read. Tail via k&8191
// (dummy stages keep the vmcnt invariant; never read).
// Swizzle (rule #21): LDS linear dest, global source chunk ^ swz4(row),
// ds_read chunk = quad ^ swz4(row)  -> <=2-way banks (free, m136).
// NO sched_barrier(0) (round-4/m141 lesson) — only empty "memory" fences
// at barriers to pin LDS-op ordering, leaving the scheduler free.
// ---------------------------------------------------------------------------
__device__ __forceinline__ void gload16(const void* g, void* l) {
    __builtin_amdgcn_global_load_lds(
        (const __attribute__((address_space(1))) void*)g,
        (__attribute__((address_space(3))) void*)l, 16, 0, 0);
}

__device__ __forceinline__ uint32_t swz4(uint32_t r) { return (r ^ (r >> 2)) & 3u; }

#define AOFFe(b,h) (((b)*2+(h))*8192)
#define BOFFe(b,h) (32768 + ((b)*2+(h))*8192)

template<int BUF, int MH, int KH, bool LOADB, bool DOWAIT, bool SISA, int SB, int SH>
__device__ __forceinline__ void phase8(uint32_t kk, __bf16* S,
    f32x4 (&acc)[8][4], bf16x8 (&bfr)[4],
    const uint32_t (&aoff)[2][4], const uint32_t (&boff)[4],
    const __bf16* gA0, const __bf16* gA1,
    const __bf16* gB0, const __bf16* gB1, uint32_t w)
{
    if (DOWAIT) asm volatile("s_waitcnt vmcnt(6)" ::: "memory");
    bf16x8 af[4];
    #pragma unroll
    for (int m = 0; m < 4; ++m)
        af[m] = *(const bf16x8*)&S[AOFFe(BUF, KH) + aoff[MH][m]];
    if (LOADB) {
        #pragma unroll
        for (int n = 0; n < 4; ++n)
            bfr[n] = *(const bf16x8*)&S[BOFFe(BUF, KH) + boff[n]];
    }
    {   // stage one half-tile (2 x 16B/lane); dest wave-uniform, linear
        const __bf16* g0 = SISA ? gA0 : gB0;
        const __bf16* g1 = SISA ? gA1 : gB1;
        const uint32_t d = (SISA ? AOFFe(SB, SH) : BOFFe(SB, SH)) + w * 512;
        gload16(g0 + kk, &S[d]);
        gload16(g1 + kk, &S[d + 4096]);
    }
    asm volatile("" ::: "memory");
    __builtin_amdgcn_s_barrier();
    asm volatile("" ::: "memory");
    __builtin_amdgcn_s_setprio(1);
    #pragma unroll
    for (int mf = 0; mf < 4; ++mf)
        #pragma unroll
        for (int nf = 0; nf < 4; ++nf)
            acc[MH * 4 + mf][nf] = __builtin_amdgcn_mfma_f32_16x16x32_bf16(
                af[mf], bfr[nf], acc[MH * 4 + mf][nf], 0, 0, 0);
    __builtin_amdgcn_s_setprio(0);
    asm volatile("" ::: "memory");
    __builtin_amdgcn_s_barrier();
    asm volatile("" ::: "memory");
}

#define PSTAGE(ISA, B, H, KK) do {                                        \
    const __bf16* g0_ = (ISA) ? gA0 : gB0;                                \
    const __bf16* g1_ = (ISA) ? gA1 : gB1;                                \
    const uint32_t d_ = ((ISA) ? AOFFe(B, H) : BOFFe(B, H)) + w * 512;    \
    gload16(g0_ + (KK), &S[d_]);                                          \
    gload16(g1_ + (KK), &S[d_ + 4096]);                                   \
} while (0)

__global__ __launch_bounds__(512) void qkv_mm8(const __bf16* __restrict__ xb,
                                               const __bf16* __restrict__ wt,
                                               float* __restrict__ out)
{
    __shared__ __align__(16) __bf16 S[65536];   // 128 KiB
    const uint32_t tid  = threadIdx.x;
    const uint32_t w    = tid >> 6;
    const uint32_t lane = tid & 63;
    const uint32_t l15  = lane & 15;
    const uint32_t quad = lane >> 4;
    const uint32_t wid_m = w >> 2;      // 0..1
    const uint32_t wid_n = w & 3;       // 0..3

    // 320 blocks = 8 mt x 40 nt, XCD-bijective (320 % 8 == 0)
    const uint32_t logical = (blockIdx.x & 7) * 40 + (blockIdx.x >> 3);
    const uint32_t mt = logical & 7;
    const uint32_t nt = logical >> 3;
    const uint32_t m0 = mt * 256;
    const uint32_t n0 = nt * 256;

    // stage source pointers: row lr, chunk pre-XOR'd by swz4(row)
    const uint32_t lr0 = tid >> 2;
    const uint32_t lr1 = 128 + lr0;
    const uint32_t pos = tid & 3;
    const __bf16* gA0 = xb + (size_t)(m0 + lr0) * K_DIM + (pos ^ swz4(lr0)) * 8;
    const __bf16* gA1 = xb + (size_t)(m0 + lr1) * K_DIM + (pos ^ swz4(lr1)) * 8;
    const __bf16* gB0 = wt + (size_t)(n0 + lr0) * K_DIM + (pos ^ swz4(lr0)) * 8;
    const __bf16* gB1 = wt + (size_t)(n0 + lr1) * K_DIM + (pos ^ swz4(lr1)) * 8;

    // fragment read offsets (elems within a [256][32] half): r*32 + (quad^swz4(r))*8
    uint32_t aoff[2][4], boff[4];
    #pragma unroll
    for (int mh = 0; mh < 2; ++mh)
        #pragma unroll
        for (int m = 0; m < 4; ++m) {
            uint32_t ar = wid_m * 128 + mh * 64 + m * 16 + l15;
            aoff[mh][m] = ar * 32 + (quad ^ swz4(ar)) * 8;
        }
    #pragma unroll
    for (int n = 0; n < 4; ++n) {
        uint32_t br = wid_n * 64 + n * 16 + l15;
        boff[n] = br * 32 + (quad ^ swz4(br)) * 8;
    }

    f32x4 acc[8][4] = {};
    bf16x8 bfr[4];

    // prologue: 6 half-tiles = tile0 (k0,k1) + tile1 (k0); drain first pair
    PSTAGE(true,  0, 0, 0);
    PSTAGE(false, 0, 0, 0);
    PSTAGE(true,  0, 1, 32);
    PSTAGE(false, 0, 1, 32);
    PSTAGE(true,  1, 0, 64);
    PSTAGE(false, 1, 0, 64);
    asm volatile("s_waitcnt vmcnt(8)" ::: "memory");
    __builtin_amdgcn_s_barrier();
    asm volatile("" ::: "memory");

    // 64 iterations x 2 K-tiles; stage map (iter i, kb=i*128):
    //  ph0: buf1.A.k1 <- kb+96   ph4: buf0.A.k1 <- kb+160
    //  ph1: buf1.B.k1 <- kb+96   ph5: buf0.B.k1 <- kb+160
    //  ph2: buf0.A.k0 <- kb+128  ph6: buf1.A.k0 <- kb+192
    //  ph3: buf0.B.k0 <- kb+128  ph7: buf1.B.k0 <- kb+192
    for (uint32_t i = 0; i < K_DIM / 128; ++i) {
        const uint32_t kb = i * 128;
        phase8<0,0,0,true ,false, true ,1,1>((kb +  96) & 8191, S, acc, bfr, aoff, boff, gA0, gA1, gB0, gB1, w);
        phase8<0,1,0,false,true , false,1,1>((kb +  96) & 8191, S, acc, bfr, aoff, boff, gA0, gA1, gB0, gB1, w);
        phase8<0,0,1,true ,false, true ,0,0>((kb + 128) & 8191, S, acc, bfr, aoff, boff, gA0, gA1, gB0, gB1, w);
        phase8<0,1,1,false,true , false,0,0>((kb + 128) & 8191, S, acc, bfr, aoff, boff, gA0, gA1, gB0, gB1, w);
        phase8<1,0,0,true ,false, true ,0,1>((kb + 160) & 8191, S, acc, bfr, aoff, boff, gA0, gA1, gB0, gB1, w);
        phase8<1,1,0,false,true , false,0,1>((kb + 160) & 8191, S, acc, bfr, aoff, boff, gA0, gA1, gB0, gB1, w);
        phase8<1,0,1,true ,false, true ,1,0>((kb + 192) & 8191, S, acc, bfr, aoff, boff, gA0, gA1, gB0, gB1, w);
        phase8<1,1,1,false,true , false,1,0>((kb + 192) & 8191, S, acc, bfr, aoff, boff, gA0, gA1, gB0, gB1, w);
    }
    asm volatile("s_waitcnt vmcnt(0)" ::: "memory");   // drain stray dummy DMAs

    // epilogue: wave covers rows [wid_m*128, +128), cols [wid_n*64, +64)
    // BN=256 spans 2 heads; head = 2*nt + (wid_n>>1) (wave-uniform)
    float* op = out + (size_t)(2 * nt + (wid_n >> 1)) * ((size_t)M_DIM * 128)
                    + (size_t)(m0 + wid_m * 128) * 128 + (wid_n & 1) * 64;
    #pragma unroll
    for (int mi = 0; mi < 8; ++mi)
        #pragma unroll
        for (int rr = 0; rr < 4; ++rr) {
            uint32_t row = mi * 16 + quad * 4 + rr;
            #pragma unroll
            for (int nf = 0; nf < 4; ++nf)
                op[(size_t)row * 128 + nf * 16 + l15] = acc[mi][nf][rr];
        }
}

// ---------------------------------------------------------------------------
// Fallback (round-0 verified kernel): used only if ws_size is too small.
// ---------------------------------------------------------------------------
#define BM 128
#define BN 128
#define BK 32
#define NIT (K_DIM / BK)

__device__ __forceinline__ uint32_t swz_fb(uint32_t r) { return ((r >> 1) ^ (r >> 3)) & 3u; }

__device__ __forceinline__ uint32_t pack_bf16(float lo, float hi) {
    bf16x2 v = { (__bf16)lo, (__bf16)hi };
    return __builtin_bit_cast(uint32_t, v);
}

__global__ __launch_bounds__(256) void qkv_gemm(
    const float* __restrict__ x,
    const float* __restrict__ wq,
    const float* __restrict__ wk,
    const float* __restrict__ wv,
    float* __restrict__ out)
{
    __shared__ __align__(16) uint16_t sA[BM * BK];
    __shared__ __align__(16) uint16_t sB[BN * BK];
    uint32_t* sAu = (uint32_t*)sA;
    uint32_t* sBu = (uint32_t*)sB;

    const uint32_t tid    = threadIdx.x;
    const uint32_t bid    = blockIdx.x;
    const uint32_t mt_blk = bid & 15;
    const uint32_t nt_blk = bid >> 4;
    const uint32_t m0     = mt_blk * BM;

    const size_t QSZ = (size_t)64 * M_DIM * 128;
    const size_t KSZ = (size_t)8  * M_DIM * 128;
    const float* Wsel;
    uint32_t ldW, col0;
    size_t obase;
    if (nt_blk < 64)      { Wsel = wq; ldW = N_Q;  col0 = nt_blk * 128;
                            obase = (size_t)nt_blk * M_DIM * 128; }
    else if (nt_blk < 72) { Wsel = wk; ldW = N_KV; col0 = (nt_blk - 64) * 128;
                            obase = QSZ + (size_t)(nt_blk - 64) * M_DIM * 128; }
    else                  { Wsel = wv; ldW = N_KV; col0 = (nt_blk - 72) * 128;
                            obase = QSZ + KSZ + (size_t)(nt_blk - 72) * M_DIM * 128; }

    const float* agp = x + (size_t)(m0 + (tid >> 3)) * K_DIM + (tid & 7) * 4;
    uint32_t a_wr[4];
    #pragma unroll
    for (int i = 0; i < 4; ++i) {
        uint32_t r = i * 32 + (tid >> 3);
        a_wr[i] = r * 16 + ((((tid >> 1) & 3) ^ swz_fb(r)) * 4) + (tid & 1) * 2;
    }

    const uint32_t bk  = (tid >> 4) * 2;
    const uint32_t bn0 = (tid & 15) * 8;
    const float* bgp = Wsel + (size_t)bk * ldW + col0 + bn0;
    const uint32_t bkc = bk >> 3;
    const uint32_t bkd = (bk & 7) >> 1;

    f32x4 apre[4], bpre[4];
    #pragma unroll
    for (int i = 0; i < 4; ++i) apre[i] = *(const f32x4*)(agp + (size_t)i * 32 * K_DIM);
    bpre[0] = *(const f32x4*)(bgp);
    bpre[1] = *(const f32x4*)(bgp + 4);
    bpre[2] = *(const f32x4*)(bgp + ldW);
    bpre[3] = *(const f32x4*)(bgp + ldW + 4);

    const uint32_t lane = tid & 63;
    const uint32_t wid  = tid >> 6;
    const uint32_t wm   = (wid >> 1) * 64;
    const uint32_t wn   = (wid & 1) * 64;
    const uint32_t l15  = lane & 15;
    const uint32_t quad = lane >> 4;

    f32x4 acc[4][4] = {};

    uint32_t a_off[4], b_off[4];
    #pragma unroll
    for (int t = 0; t < 4; ++t) {
        uint32_t ar = wm + t * 16 + l15;
        a_off[t] = ar * BK + ((quad ^ swz_fb(ar)) * 8);
        uint32_t br = wn + t * 16 + l15;
        b_off[t] = br * BK + ((quad ^ swz_fb(br)) * 8);
    }

    const float* agp_n = agp + BK;
    const float* bgp_n = bgp + (size_t)BK * ldW;

    for (uint32_t kt = 0; kt < NIT; ++kt) {
        __syncthreads();

        #pragma unroll
        for (int i = 0; i < 4; ++i) {
            uint2 wv2;
            wv2.x = pack_bf16(apre[i].x, apre[i].y);
            wv2.y = pack_bf16(apre[i].z, apre[i].w);
            *(uint2*)&sAu[a_wr[i]] = wv2;
        }
        {
            const float* pk0 = (const float*)&bpre[0];
            const float* pk1 = (const float*)&bpre[2];
            #pragma unroll
            for (int j = 0; j < 8; ++j) {
                uint32_t n = bn0 + j;
                sBu[n * 16 + ((bkc ^ swz_fb(n)) * 4) + bkd] = pack_bf16(pk0[j], pk1[j]);
            }
        }

        if (kt + 1 < NIT) {
            #pragma unroll
            for (int i = 0; i < 4; ++i) apre[i] = *(const f32x4*)(agp_n + (size_t)i * 32 * K_DIM);
            bpre[0] = *(const f32x4*)(bgp_n);
            bpre[1] = *(const f32x4*)(bgp_n + 4);
            bpre[2] = *(const f32x4*)(bgp_n + ldW);
            bpre[3] = *(const f32x4*)(bgp_n + ldW + 4);
            agp_n += BK;
            bgp_n += (size_t)BK * ldW;
        }

        __syncthreads();

        bf16x8 af[4], bf[4];
        #pragma unroll
        for (int t = 0; t < 4; ++t) {
            af[t] = *(const bf16x8*)(sA + a_off[t]);
            bf[t] = *(const bf16x8*)(sB + b_off[t]);
        }
        #pragma unroll
        for (int mi = 0; mi < 4; ++mi)
            #pragma unroll
            for (int ni = 0; ni < 4; ++ni)
                acc[mi][ni] = __builtin_amdgcn_mfma_f32_16x16x32_bf16(
                    af[mi], bf[ni], acc[mi][ni], 0, 0, 0);
    }

    float* op = out + obase + (size_t)m0 * 128;
    #pragma unroll
    for (int mi = 0; mi < 4; ++mi) {
        #pragma unroll
        for (int r = 0; r < 4; ++r) {
            uint32_t row = wm + mi * 16 + quad * 4 + r;
            #pragma unroll
            for (int ni = 0; ni < 4; ++ni) {
                uint32_t col = wn + ni * 16 + l15;
                op[(size_t)row * 128 + col] = acc[mi][ni][r];
            }
        }
    }
}

extern "C" void kernel_launch(void* const* d_in, const int* in_sizes, int n_in,
                              void* d_out, int out_size, void* d_ws, size_t ws_size,
                              hipStream_t stream) {
    const float* x  = (const float*)d_in[0];
    const float* wq = (const float*)d_in[1];
    const float* wk = (const float*)d_in[2];
    const float* wv = (const float*)d_in[3];

    const size_t XB_BYTES = (size_t)M_DIM * K_DIM * 2;          //  33.6 MB
    const size_t WT_BYTES = (size_t)N_TOT * K_DIM * 2;          // 167.8 MB

    if (ws_size >= XB_BYTES + WT_BYTES) {
        __bf16* xb = (__bf16*)d_ws;
        __bf16* wt = (__bf16*)((char*)d_ws + XB_BYTES);
        xcast<<<dim3((M_DIM * K_DIM) / (256 * 8)), dim3(256), 0, stream>>>(x, xb);
        wcast_t<<<dim3((K_DIM / 64) * (N_TOT / 64)), dim3(256), 0, stream>>>(wq, wk, wv, wt);
        qkv_mm8<<<dim3((M_DIM / 256) * (N_TOT / 256)), dim3(512), 0, stream>>>(xb, wt, (float*)d_out);
    } else {
        qkv_gemm<<<dim3((M_DIM / BM) * (N_TOT / BN)), dim3(256), 0, stream>>>(
            x, wq, wk, wv, (float*)d_out);
    }
}

// Round 6
// 886.196 us; speedup vs baseline: 1.0784x; 1.0659x over previous
//
#include <hip/hip_runtime.h>
#include <stdint.h>

#define M_DIM 2048
#define K_DIM 8192
#define N_Q   8192
#define N_KV  1024
#define N_TOT (N_Q + 2 * N_KV)   // 10240

typedef __bf16 bf16x8 __attribute__((ext_vector_type(8)));
typedef __bf16 bf16x2 __attribute__((ext_vector_type(2)));
typedef float  f32x4  __attribute__((ext_vector_type(4)));

// ---------------------------------------------------------------------------
// Pass 1a: cast x f32 -> bf16 (verified r2/r3, unchanged)
// ---------------------------------------------------------------------------
__global__ __launch_bounds__(256) void xcast(const float* __restrict__ x,
                                             __bf16* __restrict__ xb) {
    size_t i = ((size_t)blockIdx.x * 256 + threadIdx.x) * 8;
    f32x4 a = *(const f32x4*)(x + i);
    f32x4 b = *(const f32x4*)(x + i + 4);
    bf16x8 o = { (__bf16)a.x, (__bf16)a.y, (__bf16)a.z, (__bf16)a.w,
                 (__bf16)b.x, (__bf16)b.y, (__bf16)b.z, (__bf16)b.w };
    *(bf16x8*)(xb + i) = o;
}

// ---------------------------------------------------------------------------
// Pass 1b: cast + transpose W -> bf16 [N][K] concat (verified r2/r3, unchanged)
// ---------------------------------------------------------------------------
__global__ __launch_bounds__(256) void wcast_t(const float* __restrict__ wq,
                                               const float* __restrict__ wk,
                                               const float* __restrict__ wv,
                                               __bf16* __restrict__ wt) {
    __shared__ float sT[64 * 65];
    const uint32_t bid   = blockIdx.x;
    const uint32_t ktile = bid & 127;
    const uint32_t ntile = bid >> 7;
    const float* W; uint32_t ldW, csrc, cdst;
    if (ntile < 128)      { W = wq; ldW = N_Q;  csrc = ntile * 64;
                            cdst = csrc; }
    else if (ntile < 144) { W = wk; ldW = N_KV; csrc = (ntile - 128) * 64;
                            cdst = N_Q + csrc; }
    else                  { W = wv; ldW = N_KV; csrc = (ntile - 144) * 64;
                            cdst = N_Q + N_KV + csrc; }
    const uint32_t k0 = ktile * 64;
    const uint32_t t  = threadIdx.x;

    const uint32_t lr = t >> 4;
    const uint32_t lc = (t & 15) * 4;
    const float* gp = W + (size_t)(k0 + lr) * ldW + csrc + lc;
    #pragma unroll
    for (int i = 0; i < 4; ++i) {
        f32x4 v = *(const f32x4*)(gp + (size_t)i * 16 * ldW);
        float* d = &sT[(lr + i * 16) * 65 + lc];
        d[0] = v.x; d[1] = v.y; d[2] = v.z; d[3] = v.w;
    }
    __syncthreads();

    const uint32_t wn  = t >> 3;
    const uint32_t wk8 = (t & 7) * 8;
    #pragma unroll
    for (int it = 0; it < 2; ++it) {
        uint32_t n = wn + it * 32;
        bf16x8 o;
        #pragma unroll
        for (int j = 0; j < 8; ++j) o[j] = (__bf16)sT[(wk8 + j) * 65 + n];
        *(bf16x8*)(wt + (size_t)(cdst + n) * K_DIM + k0 + wk8) = o;
    }
}

// ---------------------------------------------------------------------------
// Pass 2: 8-phase 256x320 bf16 GEMM — r5's verified schedule, re-tiled so the
// grid is EXACTLY 256 blocks (8 mt x 32 nt) = 1 block/CU, zero tail (r5's 320
// blocks @ 1/CU = 62.5% grid efficiency was the bottleneck).
// 8 waves (2M x 4N), per-wave 128x80 out (5 N-frags, 20 MFMA/phase).
// LDS 144 KiB: A[2buf][2kh][256][32] | B[2buf][2kh][320][32] (bf16).
// Staging: slot (buf,kh) = A-half 16KB (2x16B events) + B-half 20KB
// (2x16B + 2x4B events; 4B stays within a 16B swizzle chunk). 3 events per
// phase uniformly -> counted wait vmcnt(9) at odd phases (r5's vmcnt(6)
// scaled 2->3 events/phase; identical slot lead of 5-6 phases, re-derived).
// Swizzle (rule #21): LDS linear dest, source chunk ^ swz4(row); ds_read
// chunk = quad ^ swz4(row) -> <=2-way banks (free, m136).
// ---------------------------------------------------------------------------
__device__ __forceinline__ void gload16(const void* g, void* l) {
    __builtin_amdgcn_global_load_lds(
        (const __attribute__((address_space(1))) void*)g,
        (__attribute__((address_space(3))) void*)l, 16, 0, 0);
}
__device__ __forceinline__ void gload4(const void* g, void* l) {
    __builtin_amdgcn_global_load_lds(
        (const __attribute__((address_space(1))) void*)g,
        (__attribute__((address_space(3))) void*)l, 4, 0, 0);
}

__device__ __forceinline__ uint32_t swz4(uint32_t r) { return (r ^ (r >> 2)) & 3u; }

template<int BUF, int MH, int KH, bool LOADB, bool DOWAIT, class F>
__device__ __forceinline__ void phase5(__bf16* S, f32x4 (&acc)[8][5],
    bf16x8 (&bfr)[5], const uint32_t (&aoff)[2][4], const uint32_t (&boff)[5],
    F&& stage)
{
    if constexpr (DOWAIT) {
        asm volatile("s_waitcnt vmcnt(9)" ::: "memory");
    }
    bf16x8 af[4];
    #pragma unroll
    for (int m = 0; m < 4; ++m)
        af[m] = *(const bf16x8*)&S[(BUF * 2 + KH) * 8192 + aoff[MH][m]];
    if constexpr (LOADB) {
        #pragma unroll
        for (int n = 0; n < 5; ++n)
            bfr[n] = *(const bf16x8*)&S[32768 + (BUF * 2 + KH) * 10240 + boff[n]];
    }
    stage();
    asm volatile("" ::: "memory");
    __builtin_amdgcn_s_barrier();
    asm volatile("" ::: "memory");
    __builtin_amdgcn_s_setprio(1);
    #pragma unroll
    for (int mf = 0; mf < 4; ++mf)
        #pragma unroll
        for (int nf = 0; nf < 5; ++nf)
            acc[MH * 4 + mf][nf] = __builtin_amdgcn_mfma_f32_16x16x32_bf16(
                af[mf], bfr[nf], acc[MH * 4 + mf][nf], 0, 0, 0);
    __builtin_amdgcn_s_setprio(0);
    asm volatile("" ::: "memory");
    __builtin_amdgcn_s_barrier();
    asm volatile("" ::: "memory");
}

// stage events: slot (b,h); A 16B j=0,1; B 16B j=0,1; B 4B q=0,1
#define STA(b,h,j,kk)  gload16(srcA[j] + (kk), &S[((b)*2+(h))*8192  + (j)*4096 + w512])
#define STB(b,h,j,kk)  gload16(srcB[j] + (kk), &S[32768 + ((b)*2+(h))*10240 + (j)*4096 + w512])
#define STB4(b,h,q,kk) gload4 (srcB4[q] + (kk), &S[32768 + ((b)*2+(h))*10240 + 8192 + (q)*1024 + w128])

__global__ __launch_bounds__(512) void qkv_mm5(const __bf16* __restrict__ xb,
                                               const __bf16* __restrict__ wt,
                                               float* __restrict__ out)
{
    __shared__ __align__(16) __bf16 S[73728];   // 144 KiB
    const uint32_t tid  = threadIdx.x;
    const uint32_t w    = tid >> 6;
    const uint32_t lane = tid & 63;
    const uint32_t l15  = lane & 15;
    const uint32_t quad = lane >> 4;
    const uint32_t wid_m = w >> 2;      // 0..1
    const uint32_t wid_n = w & 3;       // 0..3
    const uint32_t w512 = w * 512;
    const uint32_t w128 = w * 128;

    // 256 blocks = 8 mt x 32 nt; bid&7 -> XCD: each XCD keeps one 4.2MB
    // A-slab (mt) L2-resident; B slabs stream via L3 (168MB < 256MB).
    const uint32_t mt = blockIdx.x & 7;
    const uint32_t nt = blockIdx.x >> 3;
    const uint32_t m0 = mt * 256;
    const uint32_t n0 = nt * 320;

    // ---- stage source pointers (pre-swizzled chunk) ----
    const __bf16* srcA[2];
    const __bf16* srcB[2];
    const __bf16* srcB4[2];
    #pragma unroll
    for (int j = 0; j < 2; ++j) {
        uint32_t r = j * 128 + (tid >> 2);
        uint32_t c = (tid & 3) ^ swz4(r);
        srcA[j] = xb + (size_t)(m0 + r) * K_DIM + c * 8;
        srcB[j] = wt + (size_t)(n0 + r) * K_DIM + c * 8;
    }
    #pragma unroll
    for (int q = 0; q < 2; ++q) {
        uint32_t r = 256 + q * 32 + (tid >> 4);
        uint32_t c = ((tid & 15) >> 2) ^ swz4(r);
        srcB4[q] = wt + (size_t)(n0 + r) * K_DIM + c * 8 + (tid & 3) * 2;
    }

    // ---- frag read offsets (within one [.][32] slot) ----
    uint32_t aoff[2][4], boff[5];
    #pragma unroll
    for (int mh = 0; mh < 2; ++mh)
        #pragma unroll
        for (int m = 0; m < 4; ++m) {
            uint32_t ar = wid_m * 128 + mh * 64 + m * 16 + l15;
            aoff[mh][m] = ar * 32 + (quad ^ swz4(ar)) * 8;
        }
    #pragma unroll
    for (int n = 0; n < 5; ++n) {
        uint32_t br = wid_n * 80 + n * 16 + l15;
        boff[n] = br * 32 + (quad ^ swz4(br)) * 8;
    }

    f32x4 acc[8][5] = {};
    bf16x8 bfr[5];

    // ---- prologue: slots (0,0) k=0, (0,1) k=32, (1,0) k=64; 18 events ----
    STA(0,0,0,0);  STA(0,0,1,0);  STB(0,0,0,0);  STB(0,0,1,0);  STB4(0,0,0,0);  STB4(0,0,1,0);
    STA(0,1,0,32); STA(0,1,1,32); STB(0,1,0,32); STB(0,1,1,32); STB4(0,1,0,32); STB4(0,1,1,32);
    STA(1,0,0,64); STA(1,0,1,64); STB(1,0,0,64); STB(1,0,1,64); STB4(1,0,0,64); STB4(1,0,1,64);
    asm volatile("s_waitcnt vmcnt(12)" ::: "memory");   // slot (0,0) done
    __builtin_amdgcn_s_barrier();
    asm volatile("" ::: "memory");

    // ---- 64 iters x 2 K-tiles; stage map (kb = i*128):
    //  ph0-1 -> slot(1,1) k=kb+96   (read ph6-7 this iter)
    //  ph2-3 -> slot(0,0) k=kb+128  (read ph0-1 next iter)
    //  ph4-5 -> slot(0,1) k=kb+160  (read ph2-3 next iter)
    //  ph6-7 -> slot(1,0) k=kb+192  (read ph4-5 next iter)
    for (uint32_t i = 0; i < K_DIM / 128; ++i) {
        const uint32_t kb = i * 128;
        const uint32_t k0 = kb + 96;              // < 8192 always (real)
        const uint32_t k1 = (kb + 128) & 8191;    // tail wraps: dummy, never read
        const uint32_t k2 = (kb + 160) & 8191;
        const uint32_t k3 = (kb + 192) & 8191;
        phase5<0,0,0,true ,false>(S, acc, bfr, aoff, boff, [&]{
            STA(1,1,0,k0); STA(1,1,1,k0); STB(1,1,0,k0); });
        phase5<0,1,0,false,true >(S, acc, bfr, aoff, boff, [&]{
            STB(1,1,1,k0); STB4(1,1,0,k0); STB4(1,1,1,k0); });
        phase5<0,0,1,true ,false>(S, acc, bfr, aoff, boff, [&]{
            STA(0,0,0,k1); STA(0,0,1,k1); STB(0,0,0,k1); });
        phase5<0,1,1,false,true >(S, acc, bfr, aoff, boff, [&]{
            STB(0,0,1,k1); STB4(0,0,0,k1); STB4(0,0,1,k1); });
        phase5<1,0,0,true ,false>(S, acc, bfr, aoff, boff, [&]{
            STA(0,1,0,k2); STA(0,1,1,k2); STB(0,1,0,k2); });
        phase5<1,1,0,false,true >(S, acc, bfr, aoff, boff, [&]{
            STB(0,1,1,k2); STB4(0,1,0,k2); STB4(0,1,1,k2); });
        phase5<1,0,1,true ,false>(S, acc, bfr, aoff, boff, [&]{
            STA(1,0,0,k3); STA(1,0,1,k3); STB(1,0,0,k3); });
        phase5<1,1,1,false,true >(S, acc, bfr, aoff, boff, [&]{
            STB(1,0,1,k3); STB4(1,0,0,k3); STB4(1,0,1,k3); });
    }
    asm volatile("s_waitcnt vmcnt(0)" ::: "memory");   // drain dummy DMAs

    // ---- epilogue: wave strip rows [m0+wid_m*128,+128) x cols [n0+wid_n*80,+80)
    // frag col base is 16-aligned and <=112 mod 128 -> never crosses a head.
    // C/D layout: col = l15, row = quad*4 + reg (m89/m91 verified)
    const uint32_t cbase = n0 + wid_n * 80;
    #pragma unroll
    for (int nf = 0; nf < 5; ++nf) {
        const uint32_t c = cbase + nf * 16;
        float* oph = out + (size_t)(c >> 7) * ((size_t)M_DIM * 128) + (c & 127) + l15;
        #pragma unroll
        for (int mi = 0; mi < 8; ++mi)
            #pragma unroll
            for (int rr = 0; rr < 4; ++rr) {
                uint32_t row = m0 + wid_m * 128 + mi * 16 + quad * 4 + rr;
                oph[(size_t)row * 128] = acc[mi][nf][rr];
            }
    }
}

// ---------------------------------------------------------------------------
// Fallback (round-0 verified kernel): used only if ws_size is too small.
// ---------------------------------------------------------------------------
#define BM 128
#define BN 128
#define BK 32
#define NIT (K_DIM / BK)

__device__ __forceinline__ uint32_t swz_fb(uint32_t r) { return ((r >> 1) ^ (r >> 3)) & 3u; }

__device__ __forceinline__ uint32_t pack_bf16(float lo, float hi) {
    bf16x2 v = { (__bf16)lo, (__bf16)hi };
    return __builtin_bit_cast(uint32_t, v);
}

__global__ __launch_bounds__(256) void qkv_gemm(
    const float* __restrict__ x,
    const float* __restrict__ wq,
    const float* __restrict__ wk,
    const float* __restrict__ wv,
    float* __restrict__ out)
{
    __shared__ __align__(16) uint16_t sA[BM * BK];
    __shared__ __align__(16) uint16_t sB[BN * BK];
    uint32_t* sAu = (uint32_t*)sA;
    uint32_t* sBu = (uint32_t*)sB;

    const uint32_t tid    = threadIdx.x;
    const uint32_t bid    = blockIdx.x;
    const uint32_t mt_blk = bid & 15;
    const uint32_t nt_blk = bid >> 4;
    const uint32_t m0     = mt_blk * BM;

    const size_t QSZ = (size_t)64 * M_DIM * 128;
    const size_t KSZ = (size_t)8  * M_DIM * 128;
    const float* Wsel;
    uint32_t ldW, col0;
    size_t obase;
    if (nt_blk < 64)      { Wsel = wq; ldW = N_Q;  col0 = nt_blk * 128;
                            obase = (size_t)nt_blk * M_DIM * 128; }
    else if (nt_blk < 72) { Wsel = wk; ldW = N_KV; col0 = (nt_blk - 64) * 128;
                            obase = QSZ + (size_t)(nt_blk - 64) * M_DIM * 128; }
    else                  { Wsel = wv; ldW = N_KV; col0 = (nt_blk - 72) * 128;
                            obase = QSZ + KSZ + (size_t)(nt_blk - 72) * M_DIM * 128; }

    const float* agp = x + (size_t)(m0 + (tid >> 3)) * K_DIM + (tid & 7) * 4;
    uint32_t a_wr[4];
    #pragma unroll
    for (int i = 0; i < 4; ++i) {
        uint32_t r = i * 32 + (tid >> 3);
        a_wr[i] = r * 16 + ((((tid >> 1) & 3) ^ swz_fb(r)) * 4) + (tid & 1) * 2;
    }

    const uint32_t bk  = (tid >> 4) * 2;
    const uint32_t bn0 = (tid & 15) * 8;
    const float* bgp = Wsel + (size_t)bk * ldW + col0 + bn0;
    const uint32_t bkc = bk >> 3;
    const uint32_t bkd = (bk & 7) >> 1;

    f32x4 apre[4], bpre[4];
    #pragma unroll
    for (int i = 0; i < 4; ++i) apre[i] = *(const f32x4*)(agp + (size_t)i * 32 * K_DIM);
    bpre[0] = *(const f32x4*)(bgp);
    bpre[1] = *(const f32x4*)(bgp + 4);
    bpre[2] = *(const f32x4*)(bgp + ldW);
    bpre[3] = *(const f32x4*)(bgp + ldW + 4);

    const uint32_t lane = tid & 63;
    const uint32_t wid  = tid >> 6;
    const uint32_t wm   = (wid >> 1) * 64;
    const uint32_t wn   = (wid & 1) * 64;
    const uint32_t l15  = lane & 15;
    const uint32_t quad = lane >> 4;

    f32x4 acc[4][4] = {};

    uint32_t a_off[4], b_off[4];
    #pragma unroll
    for (int t = 0; t < 4; ++t) {
        uint32_t ar = wm + t * 16 + l15;
        a_off[t] = ar * BK + ((quad ^ swz_fb(ar)) * 8);
        uint32_t br = wn + t * 16 + l15;
        b_off[t] = br * BK + ((quad ^ swz_fb(br)) * 8);
    }

    const float* agp_n = agp + BK;
    const float* bgp_n = bgp + (size_t)BK * ldW;

    for (uint32_t kt = 0; kt < NIT; ++kt) {
        __syncthreads();

        #pragma unroll
        for (int i = 0; i < 4; ++i) {
            uint2 wv2;
            wv2.x = pack_bf16(apre[i].x, apre[i].y);
            wv2.y = pack_bf16(apre[i].z, apre[i].w);
            *(uint2*)&sAu[a_wr[i]] = wv2;
        }
        {
            const float* pk0 = (const float*)&bpre[0];
            const float* pk1 = (const float*)&bpre[2];
            #pragma unroll
            for (int j = 0; j < 8; ++j) {
                uint32_t n = bn0 + j;
                sBu[n * 16 + ((bkc ^ swz_fb(n)) * 4) + bkd] = pack_bf16(pk0[j], pk1[j]);
            }
        }

        if (kt + 1 < NIT) {
            #pragma unroll
            for (int i = 0; i < 4; ++i) apre[i] = *(const f32x4*)(agp_n + (size_t)i * 32 * K_DIM);
            bpre[0] = *(const f32x4*)(bgp_n);
            bpre[1] = *(const f32x4*)(bgp_n + 4);
            bpre[2] = *(const f32x4*)(bgp_n + ldW);
            bpre[3] = *(const f32x4*)(bgp_n + ldW + 4);
            agp_n += BK;
            bgp_n += (size_t)BK * ldW;
        }

        __syncthreads();

        bf16x8 af[4], bf[4];
        #pragma unroll
        for (int t = 0; t < 4; ++t) {
            af[t] = *(const bf16x8*)(sA + a_off[t]);
            bf[t] = *(const bf16x8*)(sB + b_off[t]);
        }
        #pragma unroll
        for (int mi = 0; mi < 4; ++mi)
            #pragma unroll
            for (int ni = 0; ni < 4; ++ni)
                acc[mi][ni] = __builtin_amdgcn_mfma_f32_16x16x32_bf16(
                    af[mi], bf[ni], acc[mi][ni], 0, 0, 0);
    }

    float* op = out + obase + (size_t)m0 * 128;
    #pragma unroll
    for (int mi = 0; mi < 4; ++mi) {
        #pragma unroll
        for (int r = 0; r < 4; ++r) {
            uint32_t row = wm + mi * 16 + quad * 4 + r;
            #pragma unroll
            for (int ni = 0; ni < 4; ++ni) {
                uint32_t col = wn + ni * 16 + l15;
                op[(size_t)row * 128 + col] = acc[mi][ni][r];
            }
        }
    }
}

extern "C" void kernel_launch(void* const* d_in, const int* in_sizes, int n_in,
                              void* d_out, int out_size, void* d_ws, size_t ws_size,
                              hipStream_t stream) {
    const float* x  = (const float*)d_in[0];
    const float* wq = (const float*)d_in[1];
    const float* wk = (const float*)d_in[2];
    const float* wv = (const float*)d_in[3];

    const size_t XB_BYTES = (size_t)M_DIM * K_DIM * 2;          //  33.6 MB
    const size_t WT_BYTES = (size_t)N_TOT * K_DIM * 2;          // 167.8 MB

    if (ws_size >= XB_BYTES + WT_BYTES) {
        __bf16* xb = (__bf16*)d_ws;
        __bf16* wt = (__bf16*)((char*)d_ws + XB_BYTES);
        xcast<<<dim3((M_DIM * K_DIM) / (256 * 8)), dim3(256), 0, stream>>>(x, xb);
        wcast_t<<<dim3((K_DIM / 64) * (N_TOT / 64)), dim3(256), 0, stream>>>(wq, wk, wv, wt);
        qkv_mm5<<<dim3((M_DIM / 256) * (N_TOT / 320)), dim3(512), 0, stream>>>(xb, wt, (float*)d_out);
    } else {
        qkv_gemm<<<dim3((M_DIM / BM) * (N_TOT / BN)), dim3(256), 0, stream>>>(
            x, wq, wk, wv, (float*)d_out);
    }
}